// Round 1
// baseline (15649.762 us; speedup 1.0000x reference)
//
#include <hip/hip_runtime.h>

#define NC 300000
#define NP 150000
#define NG 2000
#define NB 500
// D = 64 floats per row = 16 float4

// ---- degree count: one int atomic per edge ----
__global__ void count_kernel(const int* __restrict__ src, int n, int* __restrict__ cnt) {
    int i = blockIdx.x * blockDim.x + threadIdx.x;
    if (i < n) atomicAdd(cnt + src[i], 1);
}

// in-place: int count -> float 1/max(cnt,1)
__global__ void invert_kernel(float* __restrict__ buf, int n) {
    int i = blockIdx.x * blockDim.x + threadIdx.x;
    if (i < n) {
        int c = ((const int*)buf)[i];
        buf[i] = 1.0f / (float)(c > 1 ? c : 1);
    }
}

// ---- edge scatter: 16 lanes per edge, float4 gather + 4x atomicAdd f32 ----
__global__ void scatter_kernel(const int* __restrict__ src, const int* __restrict__ dst,
                               const float4* __restrict__ tgt,  // row = 16 float4
                               float* __restrict__ out,         // row = 64 floats
                               const float* __restrict__ inv,   // per-src 1/deg
                               float w, int n) {
    int t = blockIdx.x * blockDim.x + threadIdx.x;
    int e = t >> 4;
    int lane = t & 15;
    if (e >= n) return;
    int s = src[e];
    int d = dst[e];
    float scale = w * inv[s];
    float4 v = tgt[(size_t)d * 16 + lane];
    float* o = out + (size_t)s * 64 + (lane << 2);
    atomicAdd(o + 0, v.x * scale);
    atomicAdd(o + 1, v.y * scale);
    atomicAdd(o + 2, v.z * scale);
    atomicAdd(o + 3, v.w * scale);
}

__global__ void add_kernel(float4* __restrict__ out, const float4* __restrict__ in, int n4) {
    int i = blockIdx.x * blockDim.x + threadIdx.x;
    if (i < n4) {
        float4 a = out[i], b = in[i];
        a.x += b.x; a.y += b.y; a.z += b.z; a.w += b.w;
        out[i] = a;
    }
}

__global__ void scale_kernel(float4* __restrict__ out, float s, int n4) {
    int i = blockIdx.x * blockDim.x + threadIdx.x;
    if (i < n4) {
        float4 a = out[i];
        a.x *= s; a.y *= s; a.z *= s; a.w *= s;
        out[i] = a;
    }
}

static inline unsigned cdiv(long long a, long long b) { return (unsigned)((a + b - 1) / b); }

extern "C" void kernel_launch(void* const* d_in, const int* in_sizes, int n_in,
                              void* d_out, int out_size, void* d_ws, size_t ws_size,
                              hipStream_t stream) {
    const float* cust_w  = (const float*)d_in[0];
    const float* prod_w  = (const float*)d_in[1];
    const float* group_w = (const float*)d_in[2];
    const float* brand_w = (const float*)d_in[3];
    const int* purch_src = (const int*)d_in[4];
    const int* purch_dst = (const int*)d_in[5];
    const int* pby_src   = (const int*)d_in[6];
    const int* pby_dst   = (const int*)d_in[7];
    const int* sim_src   = (const int*)d_in[8];
    const int* sim_dst   = (const int*)d_in[9];
    const int* cop_src   = (const int*)d_in[10];
    const int* cop_dst   = (const int*)d_in[11];
    const int* bel_src   = (const int*)d_in[12];
    const int* bel_dst   = (const int*)d_in[13];
    const int* comp_src  = (const int*)d_in[14];
    const int* comp_dst  = (const int*)d_in[15];

    const int n_purch = in_sizes[4];
    const int n_pby   = in_sizes[6];
    const int n_sim   = in_sizes[8];
    const int n_cop   = in_sizes[10];
    const int n_bel   = in_sizes[12];
    const int n_comp  = in_sizes[14];

    const size_t CSZ = (size_t)NC * 64;   // 19,200,000
    const size_t PSZ = (size_t)NP * 64;   //  9,600,000

    float* ws = (float*)d_ws;
    float* cA = ws;
    float* cB = cA + CSZ;
    float* pA = cB + CSZ;
    float* pB = pA + PSZ;
    float* inv_purch = pB + PSZ;          // NC
    float* inv_pby   = inv_purch + NC;    // NP
    float* inv_sim   = inv_pby + NP;
    float* inv_cop   = inv_sim + NP;
    float* inv_bel   = inv_cop + NP;
    float* inv_comp  = inv_bel + NP;
    const size_t INV_TOTAL = (size_t)NC + 5 * (size_t)NP;   // 1,050,000

    float* out_c = (float*)d_out;
    float* out_p = out_c + CSZ;
    float* out_g = out_p + PSZ;
    float* out_b = out_g + (size_t)NG * 64;

    const int BT = 256;

    // ---- degrees (layer-invariant): count then invert ----
    hipMemsetAsync(inv_purch, 0, INV_TOTAL * sizeof(float), stream);
    count_kernel<<<cdiv(n_purch, BT), BT, 0, stream>>>(purch_src, n_purch, (int*)inv_purch);
    count_kernel<<<cdiv(n_pby,   BT), BT, 0, stream>>>(pby_src,   n_pby,   (int*)inv_pby);
    count_kernel<<<cdiv(n_sim,   BT), BT, 0, stream>>>(sim_src,   n_sim,   (int*)inv_sim);
    count_kernel<<<cdiv(n_cop,   BT), BT, 0, stream>>>(cop_src,   n_cop,   (int*)inv_cop);
    count_kernel<<<cdiv(n_bel,   BT), BT, 0, stream>>>(bel_src,   n_bel,   (int*)inv_bel);
    count_kernel<<<cdiv(n_comp,  BT), BT, 0, stream>>>(comp_src,  n_comp,  (int*)inv_comp);
    invert_kernel<<<cdiv(INV_TOTAL, BT), BT, 0, stream>>>(inv_purch, (int)INV_TOTAL);

    // ---- seed outputs with layer-0 embeddings ----
    hipMemcpyAsync(out_c, cust_w,  CSZ * sizeof(float), hipMemcpyDeviceToDevice, stream);
    hipMemcpyAsync(out_p, prod_w,  PSZ * sizeof(float), hipMemcpyDeviceToDevice, stream);
    hipMemcpyAsync(out_g, group_w, (size_t)NG * 64 * sizeof(float), hipMemcpyDeviceToDevice, stream);
    hipMemcpyAsync(out_b, brand_w, (size_t)NB * 64 * sizeof(float), hipMemcpyDeviceToDevice, stream);

    // ---- 3 layers, ping-pong buffers ----
    const float* cc = cust_w;  const float* pc = prod_w;
    float* cn = cA;            float* pn = pA;
    for (int layer = 0; layer < 3; ++layer) {
        hipMemsetAsync(cn, 0, CSZ * sizeof(float), stream);
        hipMemcpyAsync(pn, pc, PSZ * sizeof(float), hipMemcpyDeviceToDevice, stream);

        // customer_next = mean over purchases of product rows
        scatter_kernel<<<cdiv((long long)n_purch * 16, BT), BT, 0, stream>>>(
            purch_src, purch_dst, (const float4*)pc, cn, inv_purch, 1.0f, n_purch);
        // product_next += mean aggs
        scatter_kernel<<<cdiv((long long)n_pby * 16, BT), BT, 0, stream>>>(
            pby_src, pby_dst, (const float4*)cc, pn, inv_pby, 1.0f, n_pby);
        scatter_kernel<<<cdiv((long long)n_sim * 16, BT), BT, 0, stream>>>(
            sim_src, sim_dst, (const float4*)pc, pn, inv_sim, 0.5f, n_sim);
        scatter_kernel<<<cdiv((long long)n_cop * 16, BT), BT, 0, stream>>>(
            cop_src, cop_dst, (const float4*)pc, pn, inv_cop, 0.3f, n_cop);
        scatter_kernel<<<cdiv((long long)n_bel * 16, BT), BT, 0, stream>>>(
            bel_src, bel_dst, (const float4*)group_w, pn, inv_bel, 0.2f, n_bel);
        scatter_kernel<<<cdiv((long long)n_comp * 16, BT), BT, 0, stream>>>(
            comp_src, comp_dst, (const float4*)brand_w, pn, inv_comp, 0.2f, n_comp);

        add_kernel<<<cdiv(CSZ / 4, BT), BT, 0, stream>>>((float4*)out_c, (const float4*)cn, (int)(CSZ / 4));
        add_kernel<<<cdiv(PSZ / 4, BT), BT, 0, stream>>>((float4*)out_p, (const float4*)pn, (int)(PSZ / 4));

        // rotate: next layer reads what we just wrote
        cc = cn; pc = pn;
        if (layer == 0) { cn = cB; pn = pB; }
        else            { cn = (cn == cB) ? cA : cB; pn = (pn == pB) ? pA : pB; }
    }

    // ---- mean over 4 snapshots (customer+product regions are contiguous) ----
    scale_kernel<<<cdiv((CSZ + PSZ) / 4, BT), BT, 0, stream>>>(
        (float4*)out_c, 0.25f, (int)((CSZ + PSZ) / 4));
}

// Round 2
// 1702.192 us; speedup vs baseline: 9.1939x; 9.1939x over previous
//
#include <hip/hip_runtime.h>

#define NC 300000
#define NP 150000
#define NG 2000
#define NB 500
#define SCAN_B 1024

static inline unsigned cdiv(long long a, long long b) { return (unsigned)((a + b - 1) / b); }

// ---- degree count: one int atomic per edge ----
__global__ void count_kernel(const int* __restrict__ src, int n, int* __restrict__ cnt) {
    int i = blockIdx.x * blockDim.x + threadIdx.x;
    if (i < n) atomicAdd(cnt + src[i], 1);
}

// ---- hierarchical exclusive scan (n <= SCAN_B * SCAN_B) ----
__global__ void scan1(const int* __restrict__ in, int* __restrict__ out,
                      int* __restrict__ bsum, int n) {
    __shared__ int sm[SCAN_B];
    int t = threadIdx.x;
    int i = blockIdx.x * SCAN_B + t;
    int v = (i < n) ? in[i] : 0;
    sm[t] = v; __syncthreads();
    for (int off = 1; off < SCAN_B; off <<= 1) {
        int add = (t >= off) ? sm[t - off] : 0;
        __syncthreads();
        sm[t] += add; __syncthreads();
    }
    if (i < n) out[i] = sm[t] - v;            // exclusive within block
    if (t == SCAN_B - 1) bsum[blockIdx.x] = sm[t];
}
__global__ void scan2(int* __restrict__ bsum, int nb) {
    __shared__ int sm[SCAN_B];
    int t = threadIdx.x;
    int v = (t < nb) ? bsum[t] : 0;
    sm[t] = v; __syncthreads();
    for (int off = 1; off < SCAN_B; off <<= 1) {
        int add = (t >= off) ? sm[t - off] : 0;
        __syncthreads();
        sm[t] += add; __syncthreads();
    }
    if (t < nb) bsum[t] = sm[t] - v;          // exclusive block offsets
}
__global__ void scan3(int* __restrict__ out, const int* __restrict__ bsum, int n) {
    int i = blockIdx.x * SCAN_B + threadIdx.x;
    if (i < n) out[i] += bsum[blockIdx.x];
}

// ---- CSR placement: bump-allocate slot within each row segment ----
__global__ void place_kernel(const int* __restrict__ src, const int* __restrict__ dst,
                             int* __restrict__ ctr, int* __restrict__ perm, int n) {
    int i = blockIdx.x * blockDim.x + threadIdx.x;
    if (i < n) {
        int p = atomicAdd(ctr + src[i], 1);
        perm[p] = dst[i];
    }
}

// ---- per-row mean aggregation term: 16 lanes own one row, float4 each ----
__device__ __forceinline__ float4 agg_row(const int* __restrict__ rp,
                                          const int* __restrict__ perm,
                                          const float4* __restrict__ tgt,
                                          int row, int lane, float w) {
    int s = rp[row], e = rp[row + 1];
    float4 acc = make_float4(0.f, 0.f, 0.f, 0.f);
    for (int i = s; i < e; ++i) {
        int d = perm[i];
        float4 v = tgt[(size_t)d * 16 + lane];
        acc.x += v.x; acc.y += v.y; acc.z += v.z; acc.w += v.w;
    }
    int deg = e - s;
    float sc = w / (float)(deg > 1 ? deg : 1);
    acc.x *= sc; acc.y *= sc; acc.z *= sc; acc.w *= sc;
    return acc;
}

// customer_next = mean over purch edges of product rows; out_c += customer_next
__global__ void cust_agg_kernel(const int* __restrict__ rp, const int* __restrict__ perm,
                                const float4* __restrict__ pc,
                                float4* __restrict__ cn, float4* __restrict__ outc,
                                int nrows) {
    int t = blockIdx.x * blockDim.x + threadIdx.x;
    int row = t >> 4;
    if (row >= nrows) return;
    int lane = t & 15;
    float4 a = agg_row(rp, perm, pc, row, lane, 1.0f);
    size_t idx = (size_t)row * 16 + lane;
    cn[idx] = a;
    float4 o = outc[idx];
    o.x += a.x; o.y += a.y; o.z += a.z; o.w += a.w;
    outc[idx] = o;
}

// product_next = pc + agg(pby,cc) + .5*agg(sim,pc) + .3*agg(cop,pc)
//                + .2*agg(bel,gw) + .2*agg(comp,bw); out_p += product_next
__global__ void prod_agg_kernel(const int* __restrict__ rp_pby, const int* __restrict__ pm_pby,
                                const int* __restrict__ rp_sim, const int* __restrict__ pm_sim,
                                const int* __restrict__ rp_cop, const int* __restrict__ pm_cop,
                                const int* __restrict__ rp_bel, const int* __restrict__ pm_bel,
                                const int* __restrict__ rp_comp, const int* __restrict__ pm_comp,
                                const float4* __restrict__ cc, const float4* __restrict__ pc,
                                const float4* __restrict__ gw, const float4* __restrict__ bw,
                                float4* __restrict__ pn, float4* __restrict__ outp,
                                int nrows) {
    int t = blockIdx.x * blockDim.x + threadIdx.x;
    int row = t >> 4;
    if (row >= nrows) return;
    int lane = t & 15;
    size_t idx = (size_t)row * 16 + lane;
    float4 acc = pc[idx];
    float4 a;
    a = agg_row(rp_pby, pm_pby, cc, row, lane, 1.0f);
    acc.x += a.x; acc.y += a.y; acc.z += a.z; acc.w += a.w;
    a = agg_row(rp_sim, pm_sim, pc, row, lane, 0.5f);
    acc.x += a.x; acc.y += a.y; acc.z += a.z; acc.w += a.w;
    a = agg_row(rp_cop, pm_cop, pc, row, lane, 0.3f);
    acc.x += a.x; acc.y += a.y; acc.z += a.z; acc.w += a.w;
    a = agg_row(rp_bel, pm_bel, gw, row, lane, 0.2f);
    acc.x += a.x; acc.y += a.y; acc.z += a.z; acc.w += a.w;
    a = agg_row(rp_comp, pm_comp, bw, row, lane, 0.2f);
    acc.x += a.x; acc.y += a.y; acc.z += a.z; acc.w += a.w;
    pn[idx] = acc;
    float4 o = outp[idx];
    o.x += acc.x; o.y += acc.y; o.z += acc.z; o.w += acc.w;
    outp[idx] = o;
}

__global__ void scale_kernel(float4* __restrict__ out, float s, int n4) {
    int i = blockIdx.x * blockDim.x + threadIdx.x;
    if (i < n4) {
        float4 a = out[i];
        a.x *= s; a.y *= s; a.z *= s; a.w *= s;
        out[i] = a;
    }
}

extern "C" void kernel_launch(void* const* d_in, const int* in_sizes, int n_in,
                              void* d_out, int out_size, void* d_ws, size_t ws_size,
                              hipStream_t stream) {
    const float* cust_w  = (const float*)d_in[0];
    const float* prod_w  = (const float*)d_in[1];
    const float* group_w = (const float*)d_in[2];
    const float* brand_w = (const float*)d_in[3];
    const int* purch_src = (const int*)d_in[4];
    const int* purch_dst = (const int*)d_in[5];
    const int* pby_src   = (const int*)d_in[6];
    const int* pby_dst   = (const int*)d_in[7];
    const int* sim_src   = (const int*)d_in[8];
    const int* sim_dst   = (const int*)d_in[9];
    const int* cop_src   = (const int*)d_in[10];
    const int* cop_dst   = (const int*)d_in[11];
    const int* bel_src   = (const int*)d_in[12];
    const int* bel_dst   = (const int*)d_in[13];
    const int* comp_src  = (const int*)d_in[14];
    const int* comp_dst  = (const int*)d_in[15];

    const int n_purch = in_sizes[4];
    const int n_pby   = in_sizes[6];
    const int n_sim   = in_sizes[8];
    const int n_cop   = in_sizes[10];
    const int n_bel   = in_sizes[12];
    const int n_comp  = in_sizes[14];

    const size_t CSZ = (size_t)NC * 64;
    const size_t PSZ = (size_t)NP * 64;

    // ---- workspace layout ----
    float* ws = (float*)d_ws;
    float* cC = ws;               // customer buffer (single, updated in place)
    float* pA = cC + CSZ;         // product ping
    float* pB = pA + PSZ;         // product pong

    const int RP_PURCH = NC + 1;
    const int RP_OTHER = NP + 1;
    const size_t RTOT = (size_t)RP_PURCH + 5 * RP_OTHER;

    int* rp_all  = (int*)(pB + PSZ);
    int* rp_purch = rp_all;
    int* rp_pby   = rp_purch + RP_PURCH;
    int* rp_sim   = rp_pby + RP_OTHER;
    int* rp_cop   = rp_sim + RP_OTHER;
    int* rp_bel   = rp_cop + RP_OTHER;
    int* rp_comp  = rp_bel + RP_OTHER;

    int* ct_all  = rp_all + RTOT;
    int* ct_purch = ct_all;
    int* ct_pby   = ct_purch + RP_PURCH;
    int* ct_sim   = ct_pby + RP_OTHER;
    int* ct_cop   = ct_sim + RP_OTHER;
    int* ct_bel   = ct_cop + RP_OTHER;
    int* ct_comp  = ct_bel + RP_OTHER;

    int* pm_all   = ct_all + RTOT;
    int* pm_purch = pm_all;
    int* pm_pby   = pm_purch + n_purch;
    int* pm_sim   = pm_pby + n_pby;
    int* pm_cop   = pm_sim + n_sim;
    int* pm_bel   = pm_cop + n_cop;
    int* pm_comp  = pm_bel + n_bel;

    int* bsum = pm_comp + n_comp;   // 1024 ints, reused sequentially

    float* out_c = (float*)d_out;
    float* out_p = out_c + CSZ;
    float* out_g = out_p + PSZ;
    float* out_b = out_g + (size_t)NG * 64;

    const int BT = 256;

    // ---- build CSR for all 6 edge sets (counts in ct_all, with zero tail slot) ----
    hipMemsetAsync(ct_all, 0, RTOT * sizeof(int), stream);
    count_kernel<<<cdiv(n_purch, BT), BT, 0, stream>>>(purch_src, n_purch, ct_purch);
    count_kernel<<<cdiv(n_pby,   BT), BT, 0, stream>>>(pby_src,   n_pby,   ct_pby);
    count_kernel<<<cdiv(n_sim,   BT), BT, 0, stream>>>(sim_src,   n_sim,   ct_sim);
    count_kernel<<<cdiv(n_cop,   BT), BT, 0, stream>>>(cop_src,   n_cop,   ct_cop);
    count_kernel<<<cdiv(n_bel,   BT), BT, 0, stream>>>(bel_src,   n_bel,   ct_bel);
    count_kernel<<<cdiv(n_comp,  BT), BT, 0, stream>>>(comp_src,  n_comp,  ct_comp);

    // exclusive scan each (cnt,+tail) -> rowptr
    {
        int ns[6]      = { RP_PURCH, RP_OTHER, RP_OTHER, RP_OTHER, RP_OTHER, RP_OTHER };
        int* ins[6]    = { ct_purch, ct_pby, ct_sim, ct_cop, ct_bel, ct_comp };
        int* outs[6]   = { rp_purch, rp_pby, rp_sim, rp_cop, rp_bel, rp_comp };
        for (int k = 0; k < 6; ++k) {
            int nb = cdiv(ns[k], SCAN_B);
            scan1<<<nb, SCAN_B, 0, stream>>>(ins[k], outs[k], bsum, ns[k]);
            scan2<<<1, SCAN_B, 0, stream>>>(bsum, nb);
            scan3<<<nb, SCAN_B, 0, stream>>>(outs[k], bsum, ns[k]);
        }
    }
    // ctr := rowptr starts (one contiguous copy), then bump-place edges
    hipMemcpyAsync(ct_all, rp_all, RTOT * sizeof(int), hipMemcpyDeviceToDevice, stream);
    place_kernel<<<cdiv(n_purch, BT), BT, 0, stream>>>(purch_src, purch_dst, ct_purch, pm_purch, n_purch);
    place_kernel<<<cdiv(n_pby,   BT), BT, 0, stream>>>(pby_src,   pby_dst,   ct_pby,   pm_pby,   n_pby);
    place_kernel<<<cdiv(n_sim,   BT), BT, 0, stream>>>(sim_src,   sim_dst,   ct_sim,   pm_sim,   n_sim);
    place_kernel<<<cdiv(n_cop,   BT), BT, 0, stream>>>(cop_src,   cop_dst,   ct_cop,   pm_cop,   n_cop);
    place_kernel<<<cdiv(n_bel,   BT), BT, 0, stream>>>(bel_src,   bel_dst,   ct_bel,   pm_bel,   n_bel);
    place_kernel<<<cdiv(n_comp,  BT), BT, 0, stream>>>(comp_src,  comp_dst,  ct_comp,  pm_comp,  n_comp);

    // ---- seed outputs with layer-0 embeddings ----
    hipMemcpyAsync(out_c, cust_w,  CSZ * sizeof(float), hipMemcpyDeviceToDevice, stream);
    hipMemcpyAsync(out_p, prod_w,  PSZ * sizeof(float), hipMemcpyDeviceToDevice, stream);
    hipMemcpyAsync(out_g, group_w, (size_t)NG * 64 * sizeof(float), hipMemcpyDeviceToDevice, stream);
    hipMemcpyAsync(out_b, brand_w, (size_t)NB * 64 * sizeof(float), hipMemcpyDeviceToDevice, stream);

    // ---- 3 layers ----
    // customer update reads only product-current, so a single customer buffer
    // suffices: run product kernel (consumes cc) BEFORE overwriting customers.
    const float* cc = cust_w;
    const float* pc = prod_w;
    float* pn = pA;
    for (int layer = 0; layer < 3; ++layer) {
        prod_agg_kernel<<<cdiv((long long)NP * 16, BT), BT, 0, stream>>>(
            rp_pby, pm_pby, rp_sim, pm_sim, rp_cop, pm_cop,
            rp_bel, pm_bel, rp_comp, pm_comp,
            (const float4*)cc, (const float4*)pc,
            (const float4*)group_w, (const float4*)brand_w,
            (float4*)pn, (float4*)out_p, NP);
        cust_agg_kernel<<<cdiv((long long)NC * 16, BT), BT, 0, stream>>>(
            rp_purch, pm_purch, (const float4*)pc,
            (float4*)cC, (float4*)out_c, NC);
        cc = cC;
        pc = pn;
        pn = (pn == pA) ? pB : pA;
    }

    // ---- mean over 4 snapshots (customer+product contiguous in d_out) ----
    scale_kernel<<<cdiv((CSZ + PSZ) / 4, BT), BT, 0, stream>>>(
        (float4*)out_c, 0.25f, (int)((CSZ + PSZ) / 4));
}

// Round 3
// 1269.186 us; speedup vs baseline: 12.3306x; 1.3412x over previous
//
#include <hip/hip_runtime.h>

#define NC 300000
#define NP 150000
#define NG 2000
#define NB 500
#define SCAN_B 1024

typedef unsigned int u32;

static inline unsigned cdiv(long long a, long long b) { return (unsigned)((a + b - 1) / b); }

// ---------- bf16 helpers (storage = packed ushort in u32 lanes) ----------
__device__ __forceinline__ float b2f(u32 h) {
    union { u32 u; float f; } c; c.u = h << 16; return c.f;
}
__device__ __forceinline__ u32 f2b(float f) {
    union { float f; u32 u; } c; c.f = f;
    return (c.u + 0x7FFFu + ((c.u >> 16) & 1u)) >> 16;   // RNE
}
__device__ __forceinline__ void unpack8(uint4 v, float* o) {
    o[0] = b2f(v.x & 0xFFFFu); o[1] = b2f(v.x >> 16);
    o[2] = b2f(v.y & 0xFFFFu); o[3] = b2f(v.y >> 16);
    o[4] = b2f(v.z & 0xFFFFu); o[5] = b2f(v.z >> 16);
    o[6] = b2f(v.w & 0xFFFFu); o[7] = b2f(v.w >> 16);
}
__device__ __forceinline__ uint4 pack8(const float* a) {
    uint4 v;
    v.x = f2b(a[0]) | (f2b(a[1]) << 16);
    v.y = f2b(a[2]) | (f2b(a[3]) << 16);
    v.z = f2b(a[4]) | (f2b(a[5]) << 16);
    v.w = f2b(a[6]) | (f2b(a[7]) << 16);
    return v;
}

// ---------- f32 -> bf16 table conversion ----------
__global__ void convert_kernel(const float* __restrict__ in, uint4* __restrict__ out, int n8) {
    int i = blockIdx.x * blockDim.x + threadIdx.x;
    if (i >= n8) return;
    const float4* p = (const float4*)(in + (size_t)i * 8);
    float4 a = p[0], b = p[1];
    float t[8] = { a.x, a.y, a.z, a.w, b.x, b.y, b.z, b.w };
    out[i] = pack8(t);
}

// ---------- CSR build ----------
__global__ void count_kernel(const int* __restrict__ src, int n, int* __restrict__ cnt) {
    int i = blockIdx.x * blockDim.x + threadIdx.x;
    if (i < n) atomicAdd(cnt + src[i], 1);
}
__global__ void scan1(const int* __restrict__ in, int* __restrict__ out,
                      int* __restrict__ bsum, int n) {
    __shared__ int sm[SCAN_B];
    int t = threadIdx.x;
    int i = blockIdx.x * SCAN_B + t;
    int v = (i < n) ? in[i] : 0;
    sm[t] = v; __syncthreads();
    for (int off = 1; off < SCAN_B; off <<= 1) {
        int add = (t >= off) ? sm[t - off] : 0;
        __syncthreads();
        sm[t] += add; __syncthreads();
    }
    if (i < n) out[i] = sm[t] - v;
    if (t == SCAN_B - 1) bsum[blockIdx.x] = sm[t];
}
__global__ void scan2(int* __restrict__ bsum, int nb) {
    __shared__ int sm[SCAN_B];
    int t = threadIdx.x;
    int v = (t < nb) ? bsum[t] : 0;
    sm[t] = v; __syncthreads();
    for (int off = 1; off < SCAN_B; off <<= 1) {
        int add = (t >= off) ? sm[t - off] : 0;
        __syncthreads();
        sm[t] += add; __syncthreads();
    }
    if (t < nb) bsum[t] = sm[t] - v;
}
__global__ void scan3(int* __restrict__ out, const int* __restrict__ bsum, int n) {
    int i = blockIdx.x * SCAN_B + threadIdx.x;
    if (i < n) out[i] += bsum[blockIdx.x];
}
__global__ void place_kernel(const int* __restrict__ src, const int* __restrict__ dst,
                             int* __restrict__ ctr, int* __restrict__ perm, int n) {
    int i = blockIdx.x * blockDim.x + threadIdx.x;
    if (i < n) {
        int p = atomicAdd(ctr + src[i], 1);
        perm[p] = dst[i];
    }
}

// ---------- mean-agg of bf16 rows, f32 accumulate ----------
__device__ __forceinline__ void agg8(const int* __restrict__ rp, const int* __restrict__ pm,
                                     const uint4* __restrict__ tgt,
                                     int row, int lane, float w, float* acc) {
    int s = rp[row], e = rp[row + 1];
    float sum[8] = {0, 0, 0, 0, 0, 0, 0, 0};
    for (int i = s; i < e; ++i) {
        int d = pm[i];
        uint4 v = tgt[(size_t)d * 8 + lane];
        float t[8]; unpack8(v, t);
        #pragma unroll
        for (int k = 0; k < 8; ++k) sum[k] += t[k];
    }
    int deg = e - s;
    float sc = w / (float)(deg > 1 ? deg : 1);
    #pragma unroll
    for (int k = 0; k < 8; ++k) acc[k] += sum[k] * sc;
}

// ---------- fused layer: product rows [0,NP), customer rows [NP,NP+NC) ----------
// mode 0 = first (seed out from current emb + acc), 1 = mid (out += acc),
// 2 = last (out = (out + acc) * 0.25, skip next-buffer write)
__global__ void layer_kernel(
    const int* __restrict__ rp_purch, const int* __restrict__ pm_purch,
    const int* __restrict__ rp_pby,   const int* __restrict__ pm_pby,
    const int* __restrict__ rp_sim,   const int* __restrict__ pm_sim,
    const int* __restrict__ rp_cop,   const int* __restrict__ pm_cop,
    const int* __restrict__ rp_bel,   const int* __restrict__ pm_bel,
    const int* __restrict__ rp_comp,  const int* __restrict__ pm_comp,
    const uint4* __restrict__ c16, const uint4* __restrict__ p16,
    const uint4* __restrict__ g16, const uint4* __restrict__ b16,
    uint4* __restrict__ c16n, uint4* __restrict__ p16n,
    float* __restrict__ outc, float* __restrict__ outp,
    int mode)
{
    int t = blockIdx.x * blockDim.x + threadIdx.x;
    int gid = t >> 3;
    int lane = t & 7;
    float acc[8];
    if (gid < NP) {
        int row = gid;
        size_t idx = (size_t)row * 8 + lane;
        float base[8]; unpack8(p16[idx], base);
        #pragma unroll
        for (int k = 0; k < 8; ++k) acc[k] = base[k];          // linear pc term
        agg8(rp_pby,  pm_pby,  c16, row, lane, 1.0f, acc);
        agg8(rp_sim,  pm_sim,  p16, row, lane, 0.5f, acc);
        agg8(rp_cop,  pm_cop,  p16, row, lane, 0.3f, acc);
        agg8(rp_bel,  pm_bel,  g16, row, lane, 0.2f, acc);
        agg8(rp_comp, pm_comp, b16, row, lane, 0.2f, acc);
        if (mode != 2) p16n[idx] = pack8(acc);
        float4* o = (float4*)(outp + (size_t)row * 64 + lane * 8);
        float4 o0, o1;
        if (mode == 0) {
            o0 = make_float4(base[0], base[1], base[2], base[3]);
            o1 = make_float4(base[4], base[5], base[6], base[7]);
        } else { o0 = o[0]; o1 = o[1]; }
        o0.x += acc[0]; o0.y += acc[1]; o0.z += acc[2]; o0.w += acc[3];
        o1.x += acc[4]; o1.y += acc[5]; o1.z += acc[6]; o1.w += acc[7];
        if (mode == 2) {
            o0.x *= 0.25f; o0.y *= 0.25f; o0.z *= 0.25f; o0.w *= 0.25f;
            o1.x *= 0.25f; o1.y *= 0.25f; o1.z *= 0.25f; o1.w *= 0.25f;
        }
        o[0] = o0; o[1] = o1;
    } else if (gid < NP + NC) {
        int row = gid - NP;
        size_t idx = (size_t)row * 8 + lane;
        #pragma unroll
        for (int k = 0; k < 8; ++k) acc[k] = 0.f;
        agg8(rp_purch, pm_purch, p16, row, lane, 1.0f, acc);
        if (mode != 2) c16n[idx] = pack8(acc);
        float4* o = (float4*)(outc + (size_t)row * 64 + lane * 8);
        float4 o0, o1;
        if (mode == 0) {
            float base[8]; unpack8(c16[idx], base);
            o0 = make_float4(base[0], base[1], base[2], base[3]);
            o1 = make_float4(base[4], base[5], base[6], base[7]);
        } else { o0 = o[0]; o1 = o[1]; }
        o0.x += acc[0]; o0.y += acc[1]; o0.z += acc[2]; o0.w += acc[3];
        o1.x += acc[4]; o1.y += acc[5]; o1.z += acc[6]; o1.w += acc[7];
        if (mode == 2) {
            o0.x *= 0.25f; o0.y *= 0.25f; o0.z *= 0.25f; o0.w *= 0.25f;
            o1.x *= 0.25f; o1.y *= 0.25f; o1.z *= 0.25f; o1.w *= 0.25f;
        }
        o[0] = o0; o[1] = o1;
    }
}

extern "C" void kernel_launch(void* const* d_in, const int* in_sizes, int n_in,
                              void* d_out, int out_size, void* d_ws, size_t ws_size,
                              hipStream_t stream) {
    const float* cust_w  = (const float*)d_in[0];
    const float* prod_w  = (const float*)d_in[1];
    const float* group_w = (const float*)d_in[2];
    const float* brand_w = (const float*)d_in[3];
    const int* purch_src = (const int*)d_in[4];
    const int* purch_dst = (const int*)d_in[5];
    const int* pby_src   = (const int*)d_in[6];
    const int* pby_dst   = (const int*)d_in[7];
    const int* sim_src   = (const int*)d_in[8];
    const int* sim_dst   = (const int*)d_in[9];
    const int* cop_src   = (const int*)d_in[10];
    const int* cop_dst   = (const int*)d_in[11];
    const int* bel_src   = (const int*)d_in[12];
    const int* bel_dst   = (const int*)d_in[13];
    const int* comp_src  = (const int*)d_in[14];
    const int* comp_dst  = (const int*)d_in[15];

    const int n_purch = in_sizes[4];
    const int n_pby   = in_sizes[6];
    const int n_sim   = in_sizes[8];
    const int n_cop   = in_sizes[10];
    const int n_bel   = in_sizes[12];
    const int n_comp  = in_sizes[14];

    const size_t CSZ = (size_t)NC * 64;
    const size_t PSZ = (size_t)NP * 64;

    // ---- workspace layout (byte-based) ----
    char* base = (char*)d_ws;
    uint4* c16A = (uint4*)base;                 base += (size_t)NC * 128;
    uint4* c16B = (uint4*)base;                 base += (size_t)NC * 128;
    uint4* p16A = (uint4*)base;                 base += (size_t)NP * 128;
    uint4* p16B = (uint4*)base;                 base += (size_t)NP * 128;
    uint4* g16  = (uint4*)base;                 base += (size_t)NG * 128;
    uint4* b16  = (uint4*)base;                 base += (size_t)NB * 128;

    const int RP_PURCH = NC + 1;
    const int RP_OTHER = NP + 1;
    const size_t RTOT = (size_t)RP_PURCH + 5 * RP_OTHER;

    int* rp_all = (int*)base;                   base += RTOT * 4;
    int* ct_all = (int*)base;                   base += RTOT * 4;
    int* pm_all = (int*)base;                   base += (size_t)(n_purch + n_pby + n_sim + n_cop + n_bel + n_comp) * 4;
    int* bsum   = (int*)base;

    int* rp_purch = rp_all;
    int* rp_pby   = rp_purch + RP_PURCH;
    int* rp_sim   = rp_pby + RP_OTHER;
    int* rp_cop   = rp_sim + RP_OTHER;
    int* rp_bel   = rp_cop + RP_OTHER;
    int* rp_comp  = rp_bel + RP_OTHER;

    int* ct_purch = ct_all;
    int* ct_pby   = ct_purch + RP_PURCH;
    int* ct_sim   = ct_pby + RP_OTHER;
    int* ct_cop   = ct_sim + RP_OTHER;
    int* ct_bel   = ct_cop + RP_OTHER;
    int* ct_comp  = ct_bel + RP_OTHER;

    int* pm_purch = pm_all;
    int* pm_pby   = pm_purch + n_purch;
    int* pm_sim   = pm_pby + n_pby;
    int* pm_cop   = pm_sim + n_sim;
    int* pm_bel   = pm_cop + n_cop;
    int* pm_comp  = pm_bel + n_bel;

    float* out_c = (float*)d_out;
    float* out_p = out_c + CSZ;
    float* out_g = out_p + PSZ;
    float* out_b = out_g + (size_t)NG * 64;

    const int BT = 256;

    // ---- convert all tables to bf16 (gather format) ----
    convert_kernel<<<cdiv((long long)NC * 8, BT), BT, 0, stream>>>(cust_w,  c16A, NC * 8);
    convert_kernel<<<cdiv((long long)NP * 8, BT), BT, 0, stream>>>(prod_w,  p16A, NP * 8);
    convert_kernel<<<cdiv((long long)NG * 8, BT), BT, 0, stream>>>(group_w, g16,  NG * 8);
    convert_kernel<<<cdiv((long long)NB * 8, BT), BT, 0, stream>>>(brand_w, b16,  NB * 8);

    // ---- build CSR for all 6 edge sets ----
    hipMemsetAsync(ct_all, 0, RTOT * sizeof(int), stream);
    count_kernel<<<cdiv(n_purch, BT), BT, 0, stream>>>(purch_src, n_purch, ct_purch);
    count_kernel<<<cdiv(n_pby,   BT), BT, 0, stream>>>(pby_src,   n_pby,   ct_pby);
    count_kernel<<<cdiv(n_sim,   BT), BT, 0, stream>>>(sim_src,   n_sim,   ct_sim);
    count_kernel<<<cdiv(n_cop,   BT), BT, 0, stream>>>(cop_src,   n_cop,   ct_cop);
    count_kernel<<<cdiv(n_bel,   BT), BT, 0, stream>>>(bel_src,   n_bel,   ct_bel);
    count_kernel<<<cdiv(n_comp,  BT), BT, 0, stream>>>(comp_src,  n_comp,  ct_comp);
    {
        int ns[6]    = { RP_PURCH, RP_OTHER, RP_OTHER, RP_OTHER, RP_OTHER, RP_OTHER };
        int* ins[6]  = { ct_purch, ct_pby, ct_sim, ct_cop, ct_bel, ct_comp };
        int* outs[6] = { rp_purch, rp_pby, rp_sim, rp_cop, rp_bel, rp_comp };
        for (int k = 0; k < 6; ++k) {
            int nb = cdiv(ns[k], SCAN_B);
            scan1<<<nb, SCAN_B, 0, stream>>>(ins[k], outs[k], bsum, ns[k]);
            scan2<<<1, SCAN_B, 0, stream>>>(bsum, nb);
            scan3<<<nb, SCAN_B, 0, stream>>>(outs[k], bsum, ns[k]);
        }
    }
    hipMemcpyAsync(ct_all, rp_all, RTOT * sizeof(int), hipMemcpyDeviceToDevice, stream);
    place_kernel<<<cdiv(n_purch, BT), BT, 0, stream>>>(purch_src, purch_dst, ct_purch, pm_purch, n_purch);
    place_kernel<<<cdiv(n_pby,   BT), BT, 0, stream>>>(pby_src,   pby_dst,   ct_pby,   pm_pby,   n_pby);
    place_kernel<<<cdiv(n_sim,   BT), BT, 0, stream>>>(sim_src,   sim_dst,   ct_sim,   pm_sim,   n_sim);
    place_kernel<<<cdiv(n_cop,   BT), BT, 0, stream>>>(cop_src,   cop_dst,   ct_cop,   pm_cop,   n_cop);
    place_kernel<<<cdiv(n_bel,   BT), BT, 0, stream>>>(bel_src,   bel_dst,   ct_bel,   pm_bel,   n_bel);
    place_kernel<<<cdiv(n_comp,  BT), BT, 0, stream>>>(comp_src,  comp_dst,  ct_comp,  pm_comp,  n_comp);

    // ---- group/brand outputs are unchanged inputs ----
    hipMemcpyAsync(out_g, group_w, (size_t)NG * 64 * sizeof(float), hipMemcpyDeviceToDevice, stream);
    hipMemcpyAsync(out_b, brand_w, (size_t)NB * 64 * sizeof(float), hipMemcpyDeviceToDevice, stream);

    // ---- 3 fused layers ----
    const long long LTHREADS = (long long)(NP + NC) * 8;
    // layer 0: cur A, next B
    layer_kernel<<<cdiv(LTHREADS, BT), BT, 0, stream>>>(
        rp_purch, pm_purch, rp_pby, pm_pby, rp_sim, pm_sim, rp_cop, pm_cop,
        rp_bel, pm_bel, rp_comp, pm_comp,
        c16A, p16A, g16, b16, c16B, p16B, out_c, out_p, 0);
    // layer 1: cur B, next A
    layer_kernel<<<cdiv(LTHREADS, BT), BT, 0, stream>>>(
        rp_purch, pm_purch, rp_pby, pm_pby, rp_sim, pm_sim, rp_cop, pm_cop,
        rp_bel, pm_bel, rp_comp, pm_comp,
        c16B, p16B, g16, b16, c16A, p16A, out_c, out_p, 1);
    // layer 2: cur A, no next, fused *0.25
    layer_kernel<<<cdiv(LTHREADS, BT), BT, 0, stream>>>(
        rp_purch, pm_purch, rp_pby, pm_pby, rp_sim, pm_sim, rp_cop, pm_cop,
        rp_bel, pm_bel, rp_comp, pm_comp,
        c16A, p16A, g16, b16, c16B, p16B, out_c, out_p, 2);
}

// Round 4
// 1186.450 us; speedup vs baseline: 13.1904x; 1.0697x over previous
//
#include <hip/hip_runtime.h>

#define NC 300000
#define NP 150000
#define NG 2000
#define NB 500
#define SCAN_B 1024   // block scans 2048 elements

typedef unsigned int u32;

static inline unsigned cdiv(long long a, long long b) { return (unsigned)((a + b - 1) / b); }

// ---------- bf16 helpers ----------
__device__ __forceinline__ float b2f(u32 h) {
    union { u32 u; float f; } c; c.u = h << 16; return c.f;
}
__device__ __forceinline__ u32 f2b(float f) {
    union { float f; u32 u; } c; c.f = f;
    return (c.u + 0x7FFFu + ((c.u >> 16) & 1u)) >> 16;   // RNE
}
__device__ __forceinline__ void unpack8(uint4 v, float* o) {
    o[0] = b2f(v.x & 0xFFFFu); o[1] = b2f(v.x >> 16);
    o[2] = b2f(v.y & 0xFFFFu); o[3] = b2f(v.y >> 16);
    o[4] = b2f(v.z & 0xFFFFu); o[5] = b2f(v.z >> 16);
    o[6] = b2f(v.w & 0xFFFFu); o[7] = b2f(v.w >> 16);
}
__device__ __forceinline__ uint4 pack8(const float* a) {
    uint4 v;
    v.x = f2b(a[0]) | (f2b(a[1]) << 16);
    v.y = f2b(a[2]) | (f2b(a[3]) << 16);
    v.z = f2b(a[4]) | (f2b(a[5]) << 16);
    v.w = f2b(a[6]) | (f2b(a[7]) << 16);
    return v;
}

// ---------- fused f32->bf16 convert of all 4 tables (+ f32 copy for g/b outputs) ----------
__global__ void convert_all(const float* __restrict__ cw, const float* __restrict__ pw,
                            const float* __restrict__ gw, const float* __restrict__ bw,
                            uint4* __restrict__ c16, uint4* __restrict__ p16,
                            uint4* __restrict__ g16, uint4* __restrict__ b16,
                            float* __restrict__ outg, float* __restrict__ outb) {
    const int C8 = NC * 8, P8 = NP * 8, G8 = NG * 8, B8 = NB * 8;
    int i = blockIdx.x * blockDim.x + threadIdx.x;
    const float* in; uint4* out16; float* cpy = nullptr; int j;
    if (i < C8)                         { in = cw; out16 = c16; j = i; }
    else if ((j = i - C8) < P8)         { in = pw; out16 = p16; }
    else if ((j = i - C8 - P8) < G8)    { in = gw; out16 = g16; cpy = outg; }
    else if ((j = i - C8 - P8 - G8) < B8){ in = bw; out16 = b16; cpy = outb; }
    else return;
    const float4* p = (const float4*)(in + (size_t)j * 8);
    float4 a = p[0], b = p[1];
    float t[8] = { a.x, a.y, a.z, a.w, b.x, b.y, b.z, b.w };
    out16[j] = pack8(t);
    if (cpy) { float4* q = (float4*)(cpy + (size_t)j * 8); q[0] = a; q[1] = b; }
}

// ---------- fused CSR build over all 6 edge sets ----------
struct Edges6 {
    const int* src[6];
    const int* dst[6];
    int cum[7];      // cumulative edge-count offsets (cum[6] = total)
    int ctbase[6];   // base index of each set's count segment in ct_all
};

__global__ void count6(Edges6 e, int* __restrict__ ct, int total) {
    int id = blockIdx.x * blockDim.x + threadIdx.x;
    if (id >= total) return;
    int k = 0;
    #pragma unroll
    for (int q = 1; q < 6; ++q) k += (id >= e.cum[q]);
    int j = id - e.cum[k];
    atomicAdd(ct + e.ctbase[k] + e.src[k][j], 1);
}

__global__ void place6(Edges6 e, int* __restrict__ ct, int* __restrict__ pm, int total) {
    int id = blockIdx.x * blockDim.x + threadIdx.x;
    if (id >= total) return;
    int k = 0;
    #pragma unroll
    for (int q = 1; q < 6; ++q) k += (id >= e.cum[q]);
    int j = id - e.cum[k];
    int p = atomicAdd(ct + e.ctbase[k] + e.src[k][j], 1);   // ct holds global row starts
    pm[p] = e.dst[k][j];
}

// ---------- global exclusive scan, 2048 elems/block ----------
__global__ void scan1(const int* __restrict__ in, int* __restrict__ out,
                      int* __restrict__ bsum, int n) {
    __shared__ int sm[SCAN_B];
    int t = threadIdx.x;
    int i0 = blockIdx.x * 2048 + 2 * t, i1 = i0 + 1;
    int v0 = (i0 < n) ? in[i0] : 0;
    int v1 = (i1 < n) ? in[i1] : 0;
    int pair = v0 + v1;
    sm[t] = pair; __syncthreads();
    for (int off = 1; off < SCAN_B; off <<= 1) {
        int add = (t >= off) ? sm[t - off] : 0;
        __syncthreads();
        sm[t] += add; __syncthreads();
    }
    int excl = sm[t] - pair;
    if (i0 < n) out[i0] = excl;
    if (i1 < n) out[i1] = excl + v0;
    if (t == SCAN_B - 1) bsum[blockIdx.x] = sm[t];
}
__global__ void scan2(int* __restrict__ bsum, int nb) {
    __shared__ int sm[SCAN_B];
    int t = threadIdx.x;
    int v = (t < nb) ? bsum[t] : 0;
    sm[t] = v; __syncthreads();
    for (int off = 1; off < SCAN_B; off <<= 1) {
        int add = (t >= off) ? sm[t - off] : 0;
        __syncthreads();
        sm[t] += add; __syncthreads();
    }
    if (t < nb) bsum[t] = sm[t] - v;
}
// adds block offsets; writes BOTH rowptr and the place-cursor copy
__global__ void scan3(int* __restrict__ rp, int* __restrict__ ct,
                      const int* __restrict__ bsum, int n) {
    int b = bsum[blockIdx.x];
    #pragma unroll
    for (int k = 0; k < 2; ++k) {
        int idx = blockIdx.x * 2048 + k * SCAN_B + threadIdx.x;
        if (idx < n) { int v = rp[idx] + b; rp[idx] = v; ct[idx] = v; }
    }
}

// ---------- mean-agg of bf16 rows, f32 accumulate, 4-deep MLP ----------
__device__ __forceinline__ void acc8(uint4 v, float* sum) {
    float t[8]; unpack8(v, t);
    #pragma unroll
    for (int k = 0; k < 8; ++k) sum[k] += t[k];
}
__device__ __forceinline__ void agg8(const int* __restrict__ rp, const int* __restrict__ pm,
                                     const uint4* __restrict__ tgt,
                                     int row, int lane, float w, float* acc) {
    int s = rp[row], e = rp[row + 1];
    float sum[8] = {0, 0, 0, 0, 0, 0, 0, 0};
    int i = s;
    for (; i + 4 <= e; i += 4) {
        int d0 = pm[i], d1 = pm[i + 1], d2 = pm[i + 2], d3 = pm[i + 3];
        uint4 v0 = tgt[(size_t)d0 * 8 + lane];
        uint4 v1 = tgt[(size_t)d1 * 8 + lane];
        uint4 v2 = tgt[(size_t)d2 * 8 + lane];
        uint4 v3 = tgt[(size_t)d3 * 8 + lane];
        acc8(v0, sum); acc8(v1, sum); acc8(v2, sum); acc8(v3, sum);
    }
    for (; i < e; ++i) {
        uint4 v = tgt[(size_t)pm[i] * 8 + lane];
        acc8(v, sum);
    }
    int deg = e - s;
    float sc = w / (float)(deg > 1 ? deg : 1);
    #pragma unroll
    for (int k = 0; k < 8; ++k) acc[k] += sum[k] * sc;
}

// ---------- fused layer ----------
// mode 0 = seed out, 1 = out += acc, 2 = out = (out+acc)*0.25 and skip next write
__global__ void layer_kernel(
    const int* __restrict__ rp_purch, const int* __restrict__ rp_pby,
    const int* __restrict__ rp_sim,   const int* __restrict__ rp_cop,
    const int* __restrict__ rp_bel,   const int* __restrict__ rp_comp,
    const int* __restrict__ pm,
    const uint4* __restrict__ c16, const uint4* __restrict__ p16,
    const uint4* __restrict__ g16, const uint4* __restrict__ b16,
    uint4* __restrict__ c16n, uint4* __restrict__ p16n,
    float* __restrict__ outc, float* __restrict__ outp,
    int mode)
{
    int t = blockIdx.x * blockDim.x + threadIdx.x;
    int gid = t >> 3;
    int lane = t & 7;
    float acc[8];
    if (gid < NP) {
        int row = gid;
        size_t idx = (size_t)row * 8 + lane;
        float base[8]; unpack8(p16[idx], base);
        #pragma unroll
        for (int k = 0; k < 8; ++k) acc[k] = base[k];
        agg8(rp_pby,  pm, c16, row, lane, 1.0f, acc);
        agg8(rp_sim,  pm, p16, row, lane, 0.5f, acc);
        agg8(rp_cop,  pm, p16, row, lane, 0.3f, acc);
        agg8(rp_bel,  pm, g16, row, lane, 0.2f, acc);
        agg8(rp_comp, pm, b16, row, lane, 0.2f, acc);
        if (mode != 2) p16n[idx] = pack8(acc);
        float4* o = (float4*)(outp + (size_t)row * 64 + lane * 8);
        float4 o0, o1;
        if (mode == 0) {
            o0 = make_float4(base[0], base[1], base[2], base[3]);
            o1 = make_float4(base[4], base[5], base[6], base[7]);
        } else { o0 = o[0]; o1 = o[1]; }
        o0.x += acc[0]; o0.y += acc[1]; o0.z += acc[2]; o0.w += acc[3];
        o1.x += acc[4]; o1.y += acc[5]; o1.z += acc[6]; o1.w += acc[7];
        if (mode == 2) {
            o0.x *= 0.25f; o0.y *= 0.25f; o0.z *= 0.25f; o0.w *= 0.25f;
            o1.x *= 0.25f; o1.y *= 0.25f; o1.z *= 0.25f; o1.w *= 0.25f;
        }
        o[0] = o0; o[1] = o1;
    } else if (gid < NP + NC) {
        int row = gid - NP;
        size_t idx = (size_t)row * 8 + lane;
        #pragma unroll
        for (int k = 0; k < 8; ++k) acc[k] = 0.f;
        agg8(rp_purch, pm, p16, row, lane, 1.0f, acc);
        if (mode != 2) c16n[idx] = pack8(acc);
        float4* o = (float4*)(outc + (size_t)row * 64 + lane * 8);
        float4 o0, o1;
        if (mode == 0) {
            float base[8]; unpack8(c16[idx], base);
            o0 = make_float4(base[0], base[1], base[2], base[3]);
            o1 = make_float4(base[4], base[5], base[6], base[7]);
        } else { o0 = o[0]; o1 = o[1]; }
        o0.x += acc[0]; o0.y += acc[1]; o0.z += acc[2]; o0.w += acc[3];
        o1.x += acc[4]; o1.y += acc[5]; o1.z += acc[6]; o1.w += acc[7];
        if (mode == 2) {
            o0.x *= 0.25f; o0.y *= 0.25f; o0.z *= 0.25f; o0.w *= 0.25f;
            o1.x *= 0.25f; o1.y *= 0.25f; o1.z *= 0.25f; o1.w *= 0.25f;
        }
        o[0] = o0; o[1] = o1;
    }
}

extern "C" void kernel_launch(void* const* d_in, const int* in_sizes, int n_in,
                              void* d_out, int out_size, void* d_ws, size_t ws_size,
                              hipStream_t stream) {
    const float* cust_w  = (const float*)d_in[0];
    const float* prod_w  = (const float*)d_in[1];
    const float* group_w = (const float*)d_in[2];
    const float* brand_w = (const float*)d_in[3];

    const int n_purch = in_sizes[4];
    const int n_pby   = in_sizes[6];
    const int n_sim   = in_sizes[8];
    const int n_cop   = in_sizes[10];
    const int n_bel   = in_sizes[12];
    const int n_comp  = in_sizes[14];
    const int n_edges[6] = { n_purch, n_pby, n_sim, n_cop, n_bel, n_comp };

    const size_t CSZ = (size_t)NC * 64;
    const size_t PSZ = (size_t)NP * 64;

    // ---- workspace layout ----
    char* base = (char*)d_ws;
    uint4* c16A = (uint4*)base;                 base += (size_t)NC * 128;
    uint4* c16B = (uint4*)base;                 base += (size_t)NC * 128;
    uint4* p16A = (uint4*)base;                 base += (size_t)NP * 128;
    uint4* p16B = (uint4*)base;                 base += (size_t)NP * 128;
    uint4* g16  = (uint4*)base;                 base += (size_t)NG * 128;
    uint4* b16  = (uint4*)base;                 base += (size_t)NB * 128;

    const int RP_PURCH = NC + 1;
    const int RP_OTHER = NP + 1;
    const int RTOT = RP_PURCH + 5 * RP_OTHER;   // 1,050,006

    int* rp_all = (int*)base;                   base += (size_t)RTOT * 4;
    int* ct_all = (int*)base;                   base += (size_t)RTOT * 4;
    long long tot_edges = 0;
    for (int k = 0; k < 6; ++k) tot_edges += n_edges[k];
    int* pm_all = (int*)base;                   base += tot_edges * 4;
    int* bsum   = (int*)base;

    int* rp_purch = rp_all;
    int* rp_pby   = rp_purch + RP_PURCH;
    int* rp_sim   = rp_pby + RP_OTHER;
    int* rp_cop   = rp_sim + RP_OTHER;
    int* rp_bel   = rp_cop + RP_OTHER;
    int* rp_comp  = rp_bel + RP_OTHER;

    float* out_c = (float*)d_out;
    float* out_p = out_c + CSZ;
    float* out_g = out_p + PSZ;
    float* out_b = out_g + (size_t)NG * 64;

    const int BT = 256;

    // ---- fused convert (also copies group/brand f32 outputs) ----
    const long long CVT = (long long)(NC + NP + NG + NB) * 8;
    convert_all<<<cdiv(CVT, BT), BT, 0, stream>>>(
        cust_w, prod_w, group_w, brand_w, c16A, p16A, g16, b16, out_g, out_b);

    // ---- fused CSR build ----
    Edges6 E;
    E.src[0] = (const int*)d_in[4];  E.dst[0] = (const int*)d_in[5];
    E.src[1] = (const int*)d_in[6];  E.dst[1] = (const int*)d_in[7];
    E.src[2] = (const int*)d_in[8];  E.dst[2] = (const int*)d_in[9];
    E.src[3] = (const int*)d_in[10]; E.dst[3] = (const int*)d_in[11];
    E.src[4] = (const int*)d_in[12]; E.dst[4] = (const int*)d_in[13];
    E.src[5] = (const int*)d_in[14]; E.dst[5] = (const int*)d_in[15];
    E.cum[0] = 0;
    for (int k = 0; k < 6; ++k) E.cum[k + 1] = E.cum[k] + n_edges[k];
    E.ctbase[0] = 0;
    E.ctbase[1] = RP_PURCH;
    for (int k = 2; k < 6; ++k) E.ctbase[k] = E.ctbase[k - 1] + RP_OTHER;
    const int TOT = E.cum[6];

    hipMemsetAsync(ct_all, 0, (size_t)RTOT * 4, stream);
    count6<<<cdiv(TOT, BT), BT, 0, stream>>>(E, ct_all, TOT);
    {
        int nb = cdiv(RTOT, 2048);   // 513
        scan1<<<nb, SCAN_B, 0, stream>>>(ct_all, rp_all, bsum, RTOT);
        scan2<<<1, SCAN_B, 0, stream>>>(bsum, nb);
        scan3<<<nb, SCAN_B, 0, stream>>>(rp_all, ct_all, bsum, RTOT);
    }
    place6<<<cdiv(TOT, BT), BT, 0, stream>>>(E, ct_all, pm_all, TOT);

    // ---- 3 fused layers ----
    const long long LTHREADS = (long long)(NP + NC) * 8;
    layer_kernel<<<cdiv(LTHREADS, BT), BT, 0, stream>>>(
        rp_purch, rp_pby, rp_sim, rp_cop, rp_bel, rp_comp, pm_all,
        c16A, p16A, g16, b16, c16B, p16B, out_c, out_p, 0);
    layer_kernel<<<cdiv(LTHREADS, BT), BT, 0, stream>>>(
        rp_purch, rp_pby, rp_sim, rp_cop, rp_bel, rp_comp, pm_all,
        c16B, p16B, g16, b16, c16A, p16A, out_c, out_p, 1);
    layer_kernel<<<cdiv(LTHREADS, BT), BT, 0, stream>>>(
        rp_purch, rp_pby, rp_sim, rp_cop, rp_bel, rp_comp, pm_all,
        c16A, p16A, g16, b16, c16B, p16B, out_c, out_p, 2);
}

// Round 5
// 1080.584 us; speedup vs baseline: 14.4827x; 1.0980x over previous
//
#include <hip/hip_runtime.h>

#define NC 300000
#define NP 150000
#define NG 2000
#define NB 500
#define SCAN_B 1024   // block scans 2048 elements
#define NR 8          // placement key ranges (one per XCD via blockIdx%8)

typedef unsigned int u32;

static inline unsigned cdiv(long long a, long long b) { return (unsigned)((a + b - 1) / b); }

// ---------- bf16 helpers ----------
__device__ __forceinline__ float b2f(u32 h) {
    union { u32 u; float f; } c; c.u = h << 16; return c.f;
}
__device__ __forceinline__ u32 f2b(float f) {
    union { float f; u32 u; } c; c.f = f;
    return (c.u + 0x7FFFu + ((c.u >> 16) & 1u)) >> 16;   // RNE
}
__device__ __forceinline__ void unpack8(uint4 v, float* o) {
    o[0] = b2f(v.x & 0xFFFFu); o[1] = b2f(v.x >> 16);
    o[2] = b2f(v.y & 0xFFFFu); o[3] = b2f(v.y >> 16);
    o[4] = b2f(v.z & 0xFFFFu); o[5] = b2f(v.z >> 16);
    o[6] = b2f(v.w & 0xFFFFu); o[7] = b2f(v.w >> 16);
}
__device__ __forceinline__ uint4 pack8(const float* a) {
    uint4 v;
    v.x = f2b(a[0]) | (f2b(a[1]) << 16);
    v.y = f2b(a[2]) | (f2b(a[3]) << 16);
    v.z = f2b(a[4]) | (f2b(a[5]) << 16);
    v.w = f2b(a[6]) | (f2b(a[7]) << 16);
    return v;
}

// ---------- fused f32->bf16 convert of all 4 tables (+ f32 copy for g/b outputs) ----------
__global__ void convert_all(const float* __restrict__ cw, const float* __restrict__ pw,
                            const float* __restrict__ gw, const float* __restrict__ bw,
                            uint4* __restrict__ c16, uint4* __restrict__ p16,
                            uint4* __restrict__ g16, uint4* __restrict__ b16,
                            float* __restrict__ outg, float* __restrict__ outb) {
    const int C8 = NC * 8, P8 = NP * 8, G8 = NG * 8, B8 = NB * 8;
    int i = blockIdx.x * blockDim.x + threadIdx.x;
    const float* in; uint4* out16; float* cpy = nullptr; int j;
    if (i < C8)                         { in = cw; out16 = c16; j = i; }
    else if ((j = i - C8) < P8)         { in = pw; out16 = p16; }
    else if ((j = i - C8 - P8) < G8)    { in = gw; out16 = g16; cpy = outg; }
    else if ((j = i - C8 - P8 - G8) < B8){ in = bw; out16 = b16; cpy = outb; }
    else return;
    const float4* p = (const float4*)(in + (size_t)j * 8);
    float4 a = p[0], b = p[1];
    float t[8] = { a.x, a.y, a.z, a.w, b.x, b.y, b.z, b.w };
    out16[j] = pack8(t);
    if (cpy) { float4* q = (float4*)(cpy + (size_t)j * 8); q[0] = a; q[1] = b; }
}

// ---------- fused CSR build over all 6 edge sets ----------
struct Edges6 {
    const int* src[6];
    const int* dst[6];
    int cum[7];      // cumulative edge-count offsets (cum[6] = total)
    int ctbase[7];   // base key of each set's count segment (ctbase[6] = RTOT)
};

__global__ void count6(Edges6 e, int* __restrict__ ct, int total) {
    int id = blockIdx.x * blockDim.x + threadIdx.x;
    if (id >= total) return;
    int k = 0;
    #pragma unroll
    for (int q = 1; q < 6; ++q) k += (id >= e.cum[q]);
    int j = id - e.cum[k];
    atomicAdd(ct + e.ctbase[k] + e.src[k][j], 1);
}

// range-partitioned placement: blocks with blockIdx%NR==r place only keys in
// range r (contiguous 1/NR of the key space). With round-robin block->XCD
// dispatch each XCD writes one dense pm region -> full-line writebacks.
// Correctness depends only on the blockIdx partition, not on XCD mapping.
__global__ void place8(Edges6 e, int* __restrict__ ct, int* __restrict__ pm,
                       int k1, int groupThreads) {
    int r = blockIdx.x & (NR - 1);
    int lo = r * k1, hi = lo + k1;
    int t0 = (blockIdx.x >> 3) * blockDim.x + threadIdx.x;
    #pragma unroll
    for (int k = 0; k < 6; ++k) {
        int kb = e.ctbase[k], ke = e.ctbase[k + 1];
        if (ke <= lo || kb >= hi) continue;        // set doesn't overlap range
        int nk = e.cum[k + 1] - e.cum[k];
        const int* __restrict__ srk = e.src[k];
        const int* __restrict__ dsk = e.dst[k];
        for (int j = t0; j < nk; j += groupThreads) {
            int key = kb + srk[j];
            if (key >= lo && key < hi) {
                int p = atomicAdd(ct + key, 1);
                pm[p] = dsk[j];
            }
        }
    }
}

// ---------- global exclusive scan, 2048 elems/block ----------
__global__ void scan1(const int* __restrict__ in, int* __restrict__ out,
                      int* __restrict__ bsum, int n) {
    __shared__ int sm[SCAN_B];
    int t = threadIdx.x;
    int i0 = blockIdx.x * 2048 + 2 * t, i1 = i0 + 1;
    int v0 = (i0 < n) ? in[i0] : 0;
    int v1 = (i1 < n) ? in[i1] : 0;
    int pair = v0 + v1;
    sm[t] = pair; __syncthreads();
    for (int off = 1; off < SCAN_B; off <<= 1) {
        int add = (t >= off) ? sm[t - off] : 0;
        __syncthreads();
        sm[t] += add; __syncthreads();
    }
    int excl = sm[t] - pair;
    if (i0 < n) out[i0] = excl;
    if (i1 < n) out[i1] = excl + v0;
    if (t == SCAN_B - 1) bsum[blockIdx.x] = sm[t];
}
__global__ void scan2(int* __restrict__ bsum, int nb) {
    __shared__ int sm[SCAN_B];
    int t = threadIdx.x;
    int v = (t < nb) ? bsum[t] : 0;
    sm[t] = v; __syncthreads();
    for (int off = 1; off < SCAN_B; off <<= 1) {
        int add = (t >= off) ? sm[t - off] : 0;
        __syncthreads();
        sm[t] += add; __syncthreads();
    }
    if (t < nb) bsum[t] = sm[t] - v;
}
// adds block offsets; writes BOTH rowptr and the place-cursor copy
__global__ void scan3(int* __restrict__ rp, int* __restrict__ ct,
                      const int* __restrict__ bsum, int n) {
    int b = bsum[blockIdx.x];
    #pragma unroll
    for (int k = 0; k < 2; ++k) {
        int idx = blockIdx.x * 2048 + k * SCAN_B + threadIdx.x;
        if (idx < n) { int v = rp[idx] + b; rp[idx] = v; ct[idx] = v; }
    }
}

// ---------- mean-agg of bf16 rows, f32 accumulate, 4-deep MLP ----------
__device__ __forceinline__ void acc8(uint4 v, float* sum) {
    float t[8]; unpack8(v, t);
    #pragma unroll
    for (int k = 0; k < 8; ++k) sum[k] += t[k];
}
__device__ __forceinline__ void agg8(const int* __restrict__ rp, const int* __restrict__ pm,
                                     const uint4* __restrict__ tgt,
                                     int row, int lane, float w, float* acc) {
    int s = rp[row], e = rp[row + 1];
    float sum[8] = {0, 0, 0, 0, 0, 0, 0, 0};
    int i = s;
    for (; i + 4 <= e; i += 4) {
        int d0 = pm[i], d1 = pm[i + 1], d2 = pm[i + 2], d3 = pm[i + 3];
        uint4 v0 = tgt[(size_t)d0 * 8 + lane];
        uint4 v1 = tgt[(size_t)d1 * 8 + lane];
        uint4 v2 = tgt[(size_t)d2 * 8 + lane];
        uint4 v3 = tgt[(size_t)d3 * 8 + lane];
        acc8(v0, sum); acc8(v1, sum); acc8(v2, sum); acc8(v3, sum);
    }
    for (; i < e; ++i) {
        uint4 v = tgt[(size_t)pm[i] * 8 + lane];
        acc8(v, sum);
    }
    int deg = e - s;
    float sc = w / (float)(deg > 1 ? deg : 1);
    #pragma unroll
    for (int k = 0; k < 8; ++k) acc[k] += sum[k] * sc;
}

// ---------- fused layer ----------
// mode 0 = seed out, 1 = out += acc, 2 = out = (out+acc)*0.25 and skip next write
__global__ void layer_kernel(
    const int* __restrict__ rp_purch, const int* __restrict__ rp_pby,
    const int* __restrict__ rp_sim,   const int* __restrict__ rp_cop,
    const int* __restrict__ rp_bel,   const int* __restrict__ rp_comp,
    const int* __restrict__ pm,
    const uint4* __restrict__ c16, const uint4* __restrict__ p16,
    const uint4* __restrict__ g16, const uint4* __restrict__ b16,
    uint4* __restrict__ c16n, uint4* __restrict__ p16n,
    float* __restrict__ outc, float* __restrict__ outp,
    int mode)
{
    int t = blockIdx.x * blockDim.x + threadIdx.x;
    int gid = t >> 3;
    int lane = t & 7;
    float acc[8];
    if (gid < NP) {
        int row = gid;
        size_t idx = (size_t)row * 8 + lane;
        float base[8]; unpack8(p16[idx], base);
        #pragma unroll
        for (int k = 0; k < 8; ++k) acc[k] = base[k];
        agg8(rp_pby,  pm, c16, row, lane, 1.0f, acc);
        agg8(rp_sim,  pm, p16, row, lane, 0.5f, acc);
        agg8(rp_cop,  pm, p16, row, lane, 0.3f, acc);
        agg8(rp_bel,  pm, g16, row, lane, 0.2f, acc);
        agg8(rp_comp, pm, b16, row, lane, 0.2f, acc);
        if (mode != 2) p16n[idx] = pack8(acc);
        float4* o = (float4*)(outp + (size_t)row * 64 + lane * 8);
        float4 o0, o1;
        if (mode == 0) {
            o0 = make_float4(base[0], base[1], base[2], base[3]);
            o1 = make_float4(base[4], base[5], base[6], base[7]);
        } else { o0 = o[0]; o1 = o[1]; }
        o0.x += acc[0]; o0.y += acc[1]; o0.z += acc[2]; o0.w += acc[3];
        o1.x += acc[4]; o1.y += acc[5]; o1.z += acc[6]; o1.w += acc[7];
        if (mode == 2) {
            o0.x *= 0.25f; o0.y *= 0.25f; o0.z *= 0.25f; o0.w *= 0.25f;
            o1.x *= 0.25f; o1.y *= 0.25f; o1.z *= 0.25f; o1.w *= 0.25f;
        }
        o[0] = o0; o[1] = o1;
    } else if (gid < NP + NC) {
        int row = gid - NP;
        size_t idx = (size_t)row * 8 + lane;
        #pragma unroll
        for (int k = 0; k < 8; ++k) acc[k] = 0.f;
        agg8(rp_purch, pm, p16, row, lane, 1.0f, acc);
        if (mode != 2) c16n[idx] = pack8(acc);
        float4* o = (float4*)(outc + (size_t)row * 64 + lane * 8);
        float4 o0, o1;
        if (mode == 0) {
            float base[8]; unpack8(c16[idx], base);
            o0 = make_float4(base[0], base[1], base[2], base[3]);
            o1 = make_float4(base[4], base[5], base[6], base[7]);
        } else { o0 = o[0]; o1 = o[1]; }
        o0.x += acc[0]; o0.y += acc[1]; o0.z += acc[2]; o0.w += acc[3];
        o1.x += acc[4]; o1.y += acc[5]; o1.z += acc[6]; o1.w += acc[7];
        if (mode == 2) {
            o0.x *= 0.25f; o0.y *= 0.25f; o0.z *= 0.25f; o0.w *= 0.25f;
            o1.x *= 0.25f; o1.y *= 0.25f; o1.z *= 0.25f; o1.w *= 0.25f;
        }
        o[0] = o0; o[1] = o1;
    }
}

extern "C" void kernel_launch(void* const* d_in, const int* in_sizes, int n_in,
                              void* d_out, int out_size, void* d_ws, size_t ws_size,
                              hipStream_t stream) {
    const float* cust_w  = (const float*)d_in[0];
    const float* prod_w  = (const float*)d_in[1];
    const float* group_w = (const float*)d_in[2];
    const float* brand_w = (const float*)d_in[3];

    const int n_purch = in_sizes[4];
    const int n_pby   = in_sizes[6];
    const int n_sim   = in_sizes[8];
    const int n_cop   = in_sizes[10];
    const int n_bel   = in_sizes[12];
    const int n_comp  = in_sizes[14];
    const int n_edges[6] = { n_purch, n_pby, n_sim, n_cop, n_bel, n_comp };

    const size_t CSZ = (size_t)NC * 64;
    const size_t PSZ = (size_t)NP * 64;

    // ---- workspace layout ----
    char* base = (char*)d_ws;
    uint4* c16A = (uint4*)base;                 base += (size_t)NC * 128;
    uint4* c16B = (uint4*)base;                 base += (size_t)NC * 128;
    uint4* p16A = (uint4*)base;                 base += (size_t)NP * 128;
    uint4* p16B = (uint4*)base;                 base += (size_t)NP * 128;
    uint4* g16  = (uint4*)base;                 base += (size_t)NG * 128;
    uint4* b16  = (uint4*)base;                 base += (size_t)NB * 128;

    const int RP_PURCH = NC + 1;
    const int RP_OTHER = NP + 1;
    const int RTOT = RP_PURCH + 5 * RP_OTHER;   // 1,050,006

    int* rp_all = (int*)base;                   base += (size_t)RTOT * 4;
    int* ct_all = (int*)base;                   base += (size_t)RTOT * 4;
    long long tot_edges = 0;
    for (int k = 0; k < 6; ++k) tot_edges += n_edges[k];
    int* pm_all = (int*)base;                   base += tot_edges * 4;
    int* bsum   = (int*)base;

    int* rp_purch = rp_all;
    int* rp_pby   = rp_purch + RP_PURCH;
    int* rp_sim   = rp_pby + RP_OTHER;
    int* rp_cop   = rp_sim + RP_OTHER;
    int* rp_bel   = rp_cop + RP_OTHER;
    int* rp_comp  = rp_bel + RP_OTHER;

    float* out_c = (float*)d_out;
    float* out_p = out_c + CSZ;
    float* out_g = out_p + PSZ;
    float* out_b = out_g + (size_t)NG * 64;

    const int BT = 256;

    // ---- fused convert (also copies group/brand f32 outputs) ----
    const long long CVT = (long long)(NC + NP + NG + NB) * 8;
    convert_all<<<cdiv(CVT, BT), BT, 0, stream>>>(
        cust_w, prod_w, group_w, brand_w, c16A, p16A, g16, b16, out_g, out_b);

    // ---- fused CSR build ----
    Edges6 E;
    E.src[0] = (const int*)d_in[4];  E.dst[0] = (const int*)d_in[5];
    E.src[1] = (const int*)d_in[6];  E.dst[1] = (const int*)d_in[7];
    E.src[2] = (const int*)d_in[8];  E.dst[2] = (const int*)d_in[9];
    E.src[3] = (const int*)d_in[10]; E.dst[3] = (const int*)d_in[11];
    E.src[4] = (const int*)d_in[12]; E.dst[4] = (const int*)d_in[13];
    E.src[5] = (const int*)d_in[14]; E.dst[5] = (const int*)d_in[15];
    E.cum[0] = 0;
    for (int k = 0; k < 6; ++k) E.cum[k + 1] = E.cum[k] + n_edges[k];
    E.ctbase[0] = 0;
    E.ctbase[1] = RP_PURCH;
    for (int k = 2; k < 6; ++k) E.ctbase[k] = E.ctbase[k - 1] + RP_OTHER;
    E.ctbase[6] = RTOT;
    const int TOT = E.cum[6];

    hipMemsetAsync(ct_all, 0, (size_t)RTOT * 4, stream);
    count6<<<cdiv(TOT, BT), BT, 0, stream>>>(E, ct_all, TOT);
    {
        int nb = cdiv(RTOT, 2048);   // 513
        scan1<<<nb, SCAN_B, 0, stream>>>(ct_all, rp_all, bsum, RTOT);
        scan2<<<1, SCAN_B, 0, stream>>>(bsum, nb);
        scan3<<<nb, SCAN_B, 0, stream>>>(rp_all, ct_all, bsum, RTOT);
    }
    {
        const int K1 = cdiv(RTOT, NR);           // 131,251 keys per range
        const int GRP = 512;                     // blocks per range-group
        const int groupThreads = GRP * BT;       // stride within a group
        place8<<<NR * GRP, BT, 0, stream>>>(E, ct_all, pm_all, K1, groupThreads);
    }

    // ---- 3 fused layers ----
    const long long LTHREADS = (long long)(NP + NC) * 8;
    layer_kernel<<<cdiv(LTHREADS, BT), BT, 0, stream>>>(
        rp_purch, rp_pby, rp_sim, rp_cop, rp_bel, rp_comp, pm_all,
        c16A, p16A, g16, b16, c16B, p16B, out_c, out_p, 0);
    layer_kernel<<<cdiv(LTHREADS, BT), BT, 0, stream>>>(
        rp_purch, rp_pby, rp_sim, rp_cop, rp_bel, rp_comp, pm_all,
        c16B, p16B, g16, b16, c16A, p16A, out_c, out_p, 1);
    layer_kernel<<<cdiv(LTHREADS, BT), BT, 0, stream>>>(
        rp_purch, rp_pby, rp_sim, rp_cop, rp_bel, rp_comp, pm_all,
        c16A, p16A, g16, b16, c16B, p16B, out_c, out_p, 2);
}